// Round 16
// baseline (381.667 us; speedup 1.0000x reference)
//
#include <hip/hip_runtime.h>
#include <cstddef>

typedef _Float16 f16;
typedef f16 f16x8 __attribute__((ext_vector_type(8)));
typedef short s16x8 __attribute__((ext_vector_type(8)));
typedef short s16x4 __attribute__((ext_vector_type(4)));
typedef float f32x4 __attribute__((ext_vector_type(4)));

#define S_LEN 1024
#define NH 16
#define HD 64
#define MROWS 8192
#define WPLANE 1048576
#define APLANE 8388608

__device__ __forceinline__ f32x4 mfma_f16(f16x8 a, f16x8 b, f32x4 c) {
  return __builtin_amdgcn_mfma_f32_16x16x32_f16(a, b, c, 0, 0, 0);
}
__device__ __forceinline__ short f2h(float x) {
  f16 h = (f16)x;
  return __builtin_bit_cast(short, h);
}
__device__ __forceinline__ float h2f(short s) {
  return (float)__builtin_bit_cast(f16, s);
}

// async global->LDS DMA, 16B/lane: lane i lands at ldsbase + i*16.
typedef const __attribute__((address_space(1))) unsigned int* as1_u32p;
typedef __attribute__((address_space(3))) unsigned int* as3_u32p;
__device__ __forceinline__ void gl_lds16(const short* g, short* l) {
  __builtin_amdgcn_global_load_lds((as1_u32p)(const void*)g,
                                   (as3_u32p)(void*)l, 16, 0, 0);
}

// ---------------------------------------------------------------------------
// All 4 weights fp32 -> packed fp16 planes in K-STEP-TILED order. (frozen)
// ---------------------------------------------------------------------------
__global__ __launch_bounds__(256) void convw4_k(
    const float* __restrict__ W0, const float* __restrict__ W1,
    const float* __restrict__ W2, const float* __restrict__ W3,
    short* __restrict__ out) {
  const int wsel = blockIdx.y;
  const float* W = wsel == 0 ? W0 : (wsel == 1 ? W1 : (wsel == 2 ? W2 : W3));
  const int i = (blockIdx.x * 256 + threadIdx.x) * 8;
  const int n = i >> 10, kg = i & 1023;
  const int dst = (((n >> 7) * 32 + (kg >> 5)) * 128 + (n & 127)) * 32 + (kg & 31);
  float xs[8];
  *(float4*)&xs[0] = *(const float4*)&W[i];
  *(float4*)&xs[4] = *(const float4*)&W[i + 4];
  s16x8 H;
#pragma unroll
  for (int j = 0; j < 8; ++j) H[j] = f2h(xs[j]);
  *(s16x8*)&out[(size_t)wsel * WPLANE + dst] = H;
}

// ---------------------------------------------------------------------------
// Activations fp32 -> fp16 planes in M-STEP-TILED order. (frozen)
// ---------------------------------------------------------------------------
__global__ __launch_bounds__(256) void conva_k(
    const float* __restrict__ A0, const float* __restrict__ A1,
    const float* __restrict__ A2, short* __restrict__ out) {
  const int asel = blockIdx.y;
  const float* A = asel == 0 ? A0 : (asel == 1 ? A1 : A2);
  const int i = (blockIdx.x * 256 + threadIdx.x) * 8;
  const int m = i >> 10, kg = i & 1023;
  const int dst = (((m >> 7) * 32 + (kg >> 5)) * 128 + (m & 127)) * 32 + (kg & 31);
  float xs[8];
  *(float4*)&xs[0] = *(const float4*)&A[i];
  *(float4*)&xs[4] = *(const float4*)&A[i + 4];
  s16x8 H;
#pragma unroll
  for (int j = 0; j < 8; ++j) H[j] = f2h(xs[j]);
  *(s16x8*)&out[(size_t)asel * APLANE + dst] = H;
}

// ---------------------------------------------------------------------------
// Merged Q/K/V projection, fp16 1-term, ALL-DMA. grid (512, 3). (frozen)
// ---------------------------------------------------------------------------
__global__ __launch_bounds__(256, 4) void qkvproj_k(
    const short* __restrict__ Apl, const short* __restrict__ Wpl,
    const float* __restrict__ bq, const float* __restrict__ bk,
    const float* __restrict__ bv, short* __restrict__ Oq,
    short* __restrict__ Ok, short* __restrict__ Ovt) {
  __shared__ __align__(16) short Ah[128][32];
  __shared__ __align__(16) short Bh[128][32];
  const int pid = blockIdx.y;
  const float* bias = pid == 0 ? bq : (pid == 1 ? bk : bv);
  const short* Ahi = Apl + (size_t)pid * APLANE;
  const short* Whi = Wpl + (size_t)pid * WPLANE;

  const int t = threadIdx.x, lane = t & 63, wid = t >> 6;
  const int wr = wid >> 1, wc = wid & 1;
  const int fr = lane & 15, fg = lane >> 4;
  const int bid = blockIdx.x;
  const int wg = (bid & 7) * 64 + (bid >> 3);
  const int bm = (wg >> 3) * 128, bn = (wg & 7) * 128;

  f32x4 acc[4][4] = {};

  for (int ks = 0; ks < 32; ++ks) {
    {
      const size_t boff = ((size_t)(bn >> 7) * 32 + ks) * 4096;
      const size_t aoff = ((size_t)(bm >> 7) * 32 + ks) * 4096;
      const int c0 = wid * 2;
      gl_lds16(&Whi[boff + (size_t)c0 * 512 + lane * 8],       &Bh[0][0] + c0 * 512);
      gl_lds16(&Whi[boff + (size_t)(c0 + 1) * 512 + lane * 8], &Bh[0][0] + (c0 + 1) * 512);
      gl_lds16(&Ahi[aoff + (size_t)c0 * 512 + lane * 8],       &Ah[0][0] + c0 * 512);
      gl_lds16(&Ahi[aoff + (size_t)(c0 + 1) * 512 + lane * 8], &Ah[0][0] + (c0 + 1) * 512);
    }
    __syncthreads();
    f16x8 ah[4], bh[4];
#pragma unroll
    for (int f = 0; f < 4; ++f) {
      ah[f] = *(const f16x8*)&Ah[wr * 64 + f * 16 + fr][fg * 8];
      bh[f] = *(const f16x8*)&Bh[wc * 64 + f * 16 + fr][fg * 8];
    }
#pragma unroll
    for (int i = 0; i < 4; ++i)
#pragma unroll
      for (int j = 0; j < 4; ++j)
        acc[i][j] = mfma_f16(ah[i], bh[j], acc[i][j]);
    __syncthreads();
  }

#pragma unroll
  for (int i = 0; i < 4; ++i) {
#pragma unroll
    for (int j = 0; j < 4; ++j) {
      const int m0 = bm + wr * 64 + i * 16 + fg * 4;
      const int n  = bn + wc * 64 + j * 16 + fr;
      const float bb = bias[n];
      const int batch = m0 >> 10, s0 = m0 & 1023;
      const int h = n >> 6, d = n & 63;
      if (pid < 2) {
        short* O = pid == 0 ? Oq : Ok;
        const size_t base = ((size_t)(batch * NH + h) * S_LEN + s0) * HD + d;
#pragma unroll
        for (int r = 0; r < 4; ++r)
          O[base + (size_t)r * HD] = f2h(acc[i][j][r] + bb);
      } else {
        s16x4 pk;
#pragma unroll
        for (int r = 0; r < 4; ++r) pk[r] = f2h(acc[i][j][r] + bb);
        *(s16x4*)&Ovt[((size_t)(batch * NH + h) * HD + d) * S_LEN + s0] = pk;
      }
    }
  }
}

// ---------------------------------------------------------------------------
// O projection, fp16 1-term, both operands DMA'd from tiled planes. (frozen)
// ---------------------------------------------------------------------------
__global__ __launch_bounds__(256, 2) void oproj_k(
    const short* __restrict__ Ahi, const short* __restrict__ Whi,
    const float* __restrict__ bias, float* __restrict__ Of) {
  __shared__ __align__(16) short Ah[128][32];
  __shared__ __align__(16) short Bh[128][32];
  const int t = threadIdx.x, lane = t & 63, wid = t >> 6;
  const int wr = wid >> 1, wc = wid & 1;
  const int fr = lane & 15, fg = lane >> 4;
  const int bid = blockIdx.x;
  const int wg = (bid & 7) * 64 + (bid >> 3);
  const int bm = (wg >> 3) * 128, bn = (wg & 7) * 128;

  f32x4 acc[4][4] = {};

  for (int ks = 0; ks < 32; ++ks) {
    {
      const size_t boff = ((size_t)(bn >> 7) * 32 + ks) * 4096;
      const size_t aoff = ((size_t)(bm >> 7) * 32 + ks) * 4096;
      const int c0 = wid * 2;
      gl_lds16(&Whi[boff + (size_t)c0 * 512 + lane * 8],       &Bh[0][0] + c0 * 512);
      gl_lds16(&Whi[boff + (size_t)(c0 + 1) * 512 + lane * 8], &Bh[0][0] + (c0 + 1) * 512);
      gl_lds16(&Ahi[aoff + (size_t)c0 * 512 + lane * 8],       &Ah[0][0] + c0 * 512);
      gl_lds16(&Ahi[aoff + (size_t)(c0 + 1) * 512 + lane * 8], &Ah[0][0] + (c0 + 1) * 512);
    }
    __syncthreads();
    f16x8 ah[4], bh[4];
#pragma unroll
    for (int f = 0; f < 4; ++f) {
      ah[f] = *(const f16x8*)&Ah[wr * 64 + f * 16 + fr][fg * 8];
      bh[f] = *(const f16x8*)&Bh[wc * 64 + f * 16 + fr][fg * 8];
    }
#pragma unroll
    for (int i = 0; i < 4; ++i)
#pragma unroll
      for (int j = 0; j < 4; ++j)
        acc[i][j] = mfma_f16(ah[i], bh[j], acc[i][j]);
    __syncthreads();
  }

#pragma unroll
  for (int i = 0; i < 4; ++i) {
#pragma unroll
    for (int j = 0; j < 4; ++j) {
      const int m0 = bm + wr * 64 + i * 16 + fg * 4;
      const int n  = bn + wc * 64 + j * 16 + fr;
      const float bb = bias[n];
#pragma unroll
      for (int r = 0; r < 4; ++r)
        Of[(size_t)(m0 + r) * 1024 + n] = acc[i][j][r] + bb;
    }
  }
}

// ---------------------------------------------------------------------------
// Fused attention, SINGLE-QK^T: 256 threads (4 waves), QBLK=16, grid 8192.
// Phase A: QK^T once (wave wk owns a 16-k quarter of each 64-k tile), exp
//   once -> unnormalized fp16 P' in LDS [16][1026] + fp32 row sums in regs.
//   K tile double-buffered + T14 reg-pipelined -> 1 barrier/kt.
// Phase B: V tile (same buffers) dbuf+T14; per kt: (a) read P', scale by
//   1/sum, coalesced fp32 attn store (16 lanes = 256 B); (b) PV MFMA with
//   UNNORMALIZED P' (A rows q, B rows d), ctx scaled by 1/sum at the end.
// ---------------------------------------------------------------------------
__global__ __launch_bounds__(256) void attn_k(
    const short* __restrict__ Qp, const short* __restrict__ Kp,
    const short* __restrict__ Vt, float* __restrict__ attn,
    short* __restrict__ Cp) {
  __shared__ __align__(16) short St[2][64][72];   // K tiles, then V tiles
  __shared__ __align__(16) short Pp[16][1026];    // unnormalized exp (fp16)
  __shared__ float sums[4][16];
  __shared__ float sinv[16];

  const int wg = blockIdx.x;                      // 8192 blocks, %8==0
  const int w  = (wg & 7) * 1024 + (wg >> 3);     // bijective XCD chunking
  const int bh = w >> 6;
  const int qb = (w & 63) * 16;
  const int batch = bh >> 4, h = bh & 15;

  const int t = threadIdx.x, lane = t & 63, wk = t >> 6;
  const int fr = lane & 15, fg = lane >> 4;
  const int srow = t >> 2, sc = (t & 3) * 16;     // 64x64 tile staging

  // Q fragments: rows q = fr (16), cols kc*32+fg*8
  f16x8 qh[2];
#pragma unroll
  for (int kc = 0; kc < 2; ++kc)
    qh[kc] = *(const f16x8*)&Qp[((size_t)bh * S_LEN + qb + fr) * HD + kc * 32 + fg * 8];

  // ---------------- phase A: QK^T + exp -> P', row sums ----------------
  float rs = 0.0f;
  {
    const size_t kb0 = ((size_t)bh * S_LEN + srow) * HD + sc;
    s16x8 kr0 = *(const s16x8*)&Kp[kb0];
    s16x8 kr1 = *(const s16x8*)&Kp[kb0 + 8];
    for (int kt = 0; kt < 16; ++kt) {
      const int b = kt & 1;
      *(s16x8*)&St[b][srow][sc] = kr0;
      *(s16x8*)&St[b][srow][sc + 8] = kr1;
      if (kt < 15) {
        const size_t kb = kb0 + (size_t)(kt + 1) * 64 * HD;
        kr0 = *(const s16x8*)&Kp[kb];
        kr1 = *(const s16x8*)&Kp[kb + 8];
      }
      __syncthreads();
      f16x8 kh[2];
#pragma unroll
      for (int kc = 0; kc < 2; ++kc)
        kh[kc] = *(const f16x8*)&St[b][wk * 16 + fr][kc * 32 + fg * 8];
      f32x4 s4 = {};
      s4 = mfma_f16(kh[0], qh[0], s4);
      s4 = mfma_f16(kh[1], qh[1], s4);
      // lane: q = fr (col), k = wk*16 + fg*4 + r (row)
      s16x4 pk;
#pragma unroll
      for (int r = 0; r < 4; ++r) {
        const float p = __expf(s4[r] * 0.125f);
        rs += p;
        pk[r] = f2h(p);
      }
      *(s16x4*)&Pp[fr][kt * 64 + wk * 16 + fg * 4] = pk;
    }
  }
  // rs holds partial sum for q=fr over this wave's k quarter -> reduce fg
  rs += __shfl_xor(rs, 16);
  rs += __shfl_xor(rs, 32);
  if (fg == 0) sums[wk][fr] = rs;
  __syncthreads();
  if (t < 16) sinv[t] = 1.0f / (sums[0][t] + sums[1][t] + sums[2][t] + sums[3][t]);
  __syncthreads();

  // ---------------- phase B: attn store + PV ----------------
  const float pinv_row = sinv[t >> 4];            // for attn store (q = t>>4)
  float pinv4[4];
#pragma unroll
  for (int r = 0; r < 4; ++r) pinv4[r] = sinv[fg * 4 + r];  // for ctx (q=fg*4+r)

  f32x4 apv = {};
  {
    const size_t vb0 = ((size_t)bh * HD + srow) * S_LEN + sc;
    s16x8 vr0 = *(const s16x8*)&Vt[vb0];
    s16x8 vr1 = *(const s16x8*)&Vt[vb0 + 8];
    for (int kt = 0; kt < 16; ++kt) {
      const int b = kt & 1;
      *(s16x8*)&St[b][srow][sc] = vr0;
      *(s16x8*)&St[b][srow][sc + 8] = vr1;
      if (kt < 15) {
        const size_t vb = vb0 + (kt + 1) * 64;
        vr0 = *(const s16x8*)&Vt[vb];
        vr1 = *(const s16x8*)&Vt[vb + 8];
      }
      __syncthreads();
      // (a) coalesced attn store: row r0 = t>>4, 16 lanes cover 256 B
      {
        const int r0 = t >> 4, c4 = (t & 15) * 4;
        const s16x4 p4 = *(const s16x4*)&Pp[r0][kt * 64 + c4];
        float4 o;
        o.x = h2f(p4[0]) * pinv_row;
        o.y = h2f(p4[1]) * pinv_row;
        o.z = h2f(p4[2]) * pinv_row;
        o.w = h2f(p4[3]) * pinv_row;
        *(float4*)&attn[((size_t)bh * S_LEN + qb + r0) * S_LEN + kt * 64 + c4] = o;
      }
      // (b) PV: A rows q=fr from P' (unnormalized), B rows d from V tile
      f16x8 af[2], bv[2];
#pragma unroll
      for (int kc = 0; kc < 2; ++kc) {
        af[kc] = *(const f16x8*)&Pp[fr][kt * 64 + kc * 32 + fg * 8];
        bv[kc] = *(const f16x8*)&St[b][wk * 16 + fr][kc * 32 + fg * 8];
      }
      apv = mfma_f16(af[0], bv[0], apv);
      apv = mfma_f16(af[1], bv[1], apv);
    }
  }

  // ctx -> fp16 plane (K-STEP-TILED) for the O-proj DMA.
  // lane: d = h*64 + wk*16 + fr (col), q = fg*4 + r (row); scale by 1/sum.
#pragma unroll
  for (int r = 0; r < 4; ++r) {
    const int m = batch * S_LEN + qb + fg * 4 + r;
    const int d = h * HD + wk * 16 + fr;
    const size_t idx =
        (((size_t)(m >> 7) * 32 + (d >> 5)) * 128 + (m & 127)) * 32 + (d & 31);
    Cp[idx] = f2h(apv[r] * pinv4[r]);
  }
}

// ---------------------------------------------------------------------------
extern "C" void kernel_launch(void* const* d_in, const int* in_sizes, int n_in,
                              void* d_out, int out_size, void* d_ws, size_t ws_size,
                              hipStream_t stream) {
  const float* query = (const float*)d_in[0];
  const float* key   = (const float*)d_in[1];
  const float* value = (const float*)d_in[2];
  const float* Wq    = (const float*)d_in[3];
  const float* bq    = (const float*)d_in[4];
  const float* Wk    = (const float*)d_in[5];
  const float* bk    = (const float*)d_in[6];
  const float* Wv    = (const float*)d_in[7];
  const float* bv    = (const float*)d_in[8];
  const float* Wo    = (const float*)d_in[9];
  const float* bo    = (const float*)d_in[10];

  float* out  = (float*)d_out;                  // [8192][1024]
  float* attn = out + (size_t)MROWS * 1024;     // [128][1024][1024]

  short* apl = (short*)d_ws;                    // 3 activation planes
  short* qp  = apl + 3 * (size_t)APLANE;        // Q/K/V fp16 outputs
  short* kp  = qp + APLANE;
  short* vt  = kp + APLANE;
  short* w4  = vt + APLANE;                     // 4 packed weight planes
  short* cx  = apl + 2 * (size_t)APLANE;        // ctx aliases av-plane (dead
                                                // after qkvproj; cross-kernel)

  const dim3 blk(256);

  convw4_k<<<dim3(512, 4), blk, 0, stream>>>(Wq, Wk, Wv, Wo, w4);
  conva_k<<<dim3(4096, 3), blk, 0, stream>>>(query, key, value, apl);
  qkvproj_k<<<dim3(512, 3), blk, 0, stream>>>(apl, w4, bq, bk, bv, qp, kp, vt);

  attn_k<<<dim3(8192), blk, 0, stream>>>(qp, kp, vt, attn, cx);

  oproj_k<<<dim3(512), blk, 0, stream>>>(cx, w4 + 3 * WPLANE, bo, out);
}

// Round 17
// 327.419 us; speedup vs baseline: 1.1657x; 1.1657x over previous
//
#include <hip/hip_runtime.h>
#include <cstddef>

typedef _Float16 f16;
typedef f16 f16x8 __attribute__((ext_vector_type(8)));
typedef short s16x8 __attribute__((ext_vector_type(8)));
typedef short s16x4 __attribute__((ext_vector_type(4)));
typedef float f32x4 __attribute__((ext_vector_type(4)));

#define S_LEN 1024
#define NH 16
#define HD 64
#define MROWS 8192
#define WPLANE 1048576
#define APLANE 8388608

__device__ __forceinline__ f32x4 mfma_f16(f16x8 a, f16x8 b, f32x4 c) {
  return __builtin_amdgcn_mfma_f32_16x16x32_f16(a, b, c, 0, 0, 0);
}
__device__ __forceinline__ short f2h(float x) {
  f16 h = (f16)x;
  return __builtin_bit_cast(short, h);
}
__device__ __forceinline__ float h2f(short s) {
  return (float)__builtin_bit_cast(f16, s);
}

// async global->LDS DMA, 16B/lane: lane i lands at ldsbase + i*16.
typedef const __attribute__((address_space(1))) unsigned int* as1_u32p;
typedef __attribute__((address_space(3))) unsigned int* as3_u32p;
__device__ __forceinline__ void gl_lds16(const short* g, short* l) {
  __builtin_amdgcn_global_load_lds((as1_u32p)(const void*)g,
                                   (as3_u32p)(void*)l, 16, 0, 0);
}

// ---------------------------------------------------------------------------
// Merged conversion kernel. grid (4096, 4):
//   y in 0..2 : activations fp32 -> fp16 plane (M-STEP-TILED), 4096 blocks
//   y == 3    : weights fp32 -> fp16 planes (K-STEP-TILED), blocks 0..2047
//               (wsel = x>>9, xb = x&511); blocks 2048+ idle.
// ---------------------------------------------------------------------------
__global__ __launch_bounds__(256) void convall_k(
    const float* __restrict__ A0, const float* __restrict__ A1,
    const float* __restrict__ A2, const float* __restrict__ W0,
    const float* __restrict__ W1, const float* __restrict__ W2,
    const float* __restrict__ W3, short* __restrict__ apl,
    short* __restrict__ w4) {
  const int y = blockIdx.y;
  if (y < 3) {
    const float* A = y == 0 ? A0 : (y == 1 ? A1 : A2);
    const int i = (blockIdx.x * 256 + threadIdx.x) * 8;
    const int m = i >> 10, kg = i & 1023;
    const int dst = (((m >> 7) * 32 + (kg >> 5)) * 128 + (m & 127)) * 32 + (kg & 31);
    float xs[8];
    *(float4*)&xs[0] = *(const float4*)&A[i];
    *(float4*)&xs[4] = *(const float4*)&A[i + 4];
    s16x8 H;
#pragma unroll
    for (int j = 0; j < 8; ++j) H[j] = f2h(xs[j]);
    *(s16x8*)&apl[(size_t)y * APLANE + dst] = H;
  } else {
    if (blockIdx.x >= 2048) return;
    const int wsel = blockIdx.x >> 9, xb = blockIdx.x & 511;
    const float* W = wsel == 0 ? W0 : (wsel == 1 ? W1 : (wsel == 2 ? W2 : W3));
    const int i = (xb * 256 + threadIdx.x) * 8;
    const int n = i >> 10, kg = i & 1023;
    const int dst = (((n >> 7) * 32 + (kg >> 5)) * 128 + (n & 127)) * 32 + (kg & 31);
    float xs[8];
    *(float4*)&xs[0] = *(const float4*)&W[i];
    *(float4*)&xs[4] = *(const float4*)&W[i + 4];
    s16x8 H;
#pragma unroll
    for (int j = 0; j < 8; ++j) H[j] = f2h(xs[j]);
    *(s16x8*)&w4[(size_t)wsel * WPLANE + dst] = H;
  }
}

// ---------------------------------------------------------------------------
// Merged Q/K/V projection, fp16 1-term, ALL-DMA. grid (512, 3). (frozen)
// ---------------------------------------------------------------------------
__global__ __launch_bounds__(256, 4) void qkvproj_k(
    const short* __restrict__ Apl, const short* __restrict__ Wpl,
    const float* __restrict__ bq, const float* __restrict__ bk,
    const float* __restrict__ bv, short* __restrict__ Oq,
    short* __restrict__ Ok, short* __restrict__ Ovt) {
  __shared__ __align__(16) short Ah[128][32];
  __shared__ __align__(16) short Bh[128][32];
  const int pid = blockIdx.y;
  const float* bias = pid == 0 ? bq : (pid == 1 ? bk : bv);
  const short* Ahi = Apl + (size_t)pid * APLANE;
  const short* Whi = Wpl + (size_t)pid * WPLANE;

  const int t = threadIdx.x, lane = t & 63, wid = t >> 6;
  const int wr = wid >> 1, wc = wid & 1;
  const int fr = lane & 15, fg = lane >> 4;
  const int bid = blockIdx.x;
  const int wg = (bid & 7) * 64 + (bid >> 3);
  const int bm = (wg >> 3) * 128, bn = (wg & 7) * 128;

  f32x4 acc[4][4] = {};

  for (int ks = 0; ks < 32; ++ks) {
    {
      const size_t boff = ((size_t)(bn >> 7) * 32 + ks) * 4096;
      const size_t aoff = ((size_t)(bm >> 7) * 32 + ks) * 4096;
      const int c0 = wid * 2;
      gl_lds16(&Whi[boff + (size_t)c0 * 512 + lane * 8],       &Bh[0][0] + c0 * 512);
      gl_lds16(&Whi[boff + (size_t)(c0 + 1) * 512 + lane * 8], &Bh[0][0] + (c0 + 1) * 512);
      gl_lds16(&Ahi[aoff + (size_t)c0 * 512 + lane * 8],       &Ah[0][0] + c0 * 512);
      gl_lds16(&Ahi[aoff + (size_t)(c0 + 1) * 512 + lane * 8], &Ah[0][0] + (c0 + 1) * 512);
    }
    __syncthreads();
    f16x8 ah[4], bh[4];
#pragma unroll
    for (int f = 0; f < 4; ++f) {
      ah[f] = *(const f16x8*)&Ah[wr * 64 + f * 16 + fr][fg * 8];
      bh[f] = *(const f16x8*)&Bh[wc * 64 + f * 16 + fr][fg * 8];
    }
#pragma unroll
    for (int i = 0; i < 4; ++i)
#pragma unroll
      for (int j = 0; j < 4; ++j)
        acc[i][j] = mfma_f16(ah[i], bh[j], acc[i][j]);
    __syncthreads();
  }

#pragma unroll
  for (int i = 0; i < 4; ++i) {
#pragma unroll
    for (int j = 0; j < 4; ++j) {
      const int m0 = bm + wr * 64 + i * 16 + fg * 4;
      const int n  = bn + wc * 64 + j * 16 + fr;
      const float bb = bias[n];
      const int batch = m0 >> 10, s0 = m0 & 1023;
      const int h = n >> 6, d = n & 63;
      if (pid < 2) {
        short* O = pid == 0 ? Oq : Ok;
        const size_t base = ((size_t)(batch * NH + h) * S_LEN + s0) * HD + d;
#pragma unroll
        for (int r = 0; r < 4; ++r)
          O[base + (size_t)r * HD] = f2h(acc[i][j][r] + bb);
      } else {
        s16x4 pk;
#pragma unroll
        for (int r = 0; r < 4; ++r) pk[r] = f2h(acc[i][j][r] + bb);
        *(s16x4*)&Ovt[((size_t)(batch * NH + h) * HD + d) * S_LEN + s0] = pk;
      }
    }
  }
}

// ---------------------------------------------------------------------------
// O projection, fp16 1-term, both operands DMA'd from tiled planes. (frozen)
// ---------------------------------------------------------------------------
__global__ __launch_bounds__(256, 2) void oproj_k(
    const short* __restrict__ Ahi, const short* __restrict__ Whi,
    const float* __restrict__ bias, float* __restrict__ Of) {
  __shared__ __align__(16) short Ah[128][32];
  __shared__ __align__(16) short Bh[128][32];
  const int t = threadIdx.x, lane = t & 63, wid = t >> 6;
  const int wr = wid >> 1, wc = wid & 1;
  const int fr = lane & 15, fg = lane >> 4;
  const int bid = blockIdx.x;
  const int wg = (bid & 7) * 64 + (bid >> 3);
  const int bm = (wg >> 3) * 128, bn = (wg & 7) * 128;

  f32x4 acc[4][4] = {};

  for (int ks = 0; ks < 32; ++ks) {
    {
      const size_t boff = ((size_t)(bn >> 7) * 32 + ks) * 4096;
      const size_t aoff = ((size_t)(bm >> 7) * 32 + ks) * 4096;
      const int c0 = wid * 2;
      gl_lds16(&Whi[boff + (size_t)c0 * 512 + lane * 8],       &Bh[0][0] + c0 * 512);
      gl_lds16(&Whi[boff + (size_t)(c0 + 1) * 512 + lane * 8], &Bh[0][0] + (c0 + 1) * 512);
      gl_lds16(&Ahi[aoff + (size_t)c0 * 512 + lane * 8],       &Ah[0][0] + c0 * 512);
      gl_lds16(&Ahi[aoff + (size_t)(c0 + 1) * 512 + lane * 8], &Ah[0][0] + (c0 + 1) * 512);
    }
    __syncthreads();
    f16x8 ah[4], bh[4];
#pragma unroll
    for (int f = 0; f < 4; ++f) {
      ah[f] = *(const f16x8*)&Ah[wr * 64 + f * 16 + fr][fg * 8];
      bh[f] = *(const f16x8*)&Bh[wc * 64 + f * 16 + fr][fg * 8];
    }
#pragma unroll
    for (int i = 0; i < 4; ++i)
#pragma unroll
      for (int j = 0; j < 4; ++j)
        acc[i][j] = mfma_f16(ah[i], bh[j], acc[i][j]);
    __syncthreads();
  }

#pragma unroll
  for (int i = 0; i < 4; ++i) {
#pragma unroll
    for (int j = 0; j < 4; ++j) {
      const int m0 = bm + wr * 64 + i * 16 + fg * 4;
      const int n  = bn + wc * 64 + j * 16 + fr;
      const float bb = bias[n];
#pragma unroll
      for (int r = 0; r < 4; ++r)
        Of[(size_t)(m0 + r) * 1024 + n] = acc[i][j][r] + bb;
    }
  }
}

// ---------------------------------------------------------------------------
// Fused attention: 512 threads (8 waves), QBLK=128, grid 1024. (R15 base)
// R17 CHANGE: pass 1 double-buffers the K tile between Kh and Pt's first 64
// rows (Pt is dead in pass 1) -> ONE barrier per kt (WAR protected by buffer
// alternation). Pass 2 unchanged. Arithmetic bit-identical to R15.
// ---------------------------------------------------------------------------
__global__ __launch_bounds__(512) void attn_k(
    const short* __restrict__ Qp, const short* __restrict__ Kp,
    const short* __restrict__ Vt, float* __restrict__ attn,
    short* __restrict__ Cp) {
  __shared__ __align__(16) short Kh[64][72];
  __shared__ __align__(16) short Vs[64][72];
  __shared__ __align__(16) short Pt[128][72];
  __shared__ float sums[2][128];
  __shared__ float sinv[128];

  const int wg = blockIdx.x;                    // 1024 blocks, 1024%8==0
  const int w  = (wg & 7) * 128 + (wg >> 3);    // bijective XCD chunking
  const int bh = w >> 3;
  const int qb = (w & 7) * 128;
  const int batch = bh >> 4, h = bh & 15;

  const int t = threadIdx.x, lane = t & 63, wid = t >> 6;
  const int wq = wid >> 1, wk = wid & 1;
  const int fr = lane & 15, fg = lane >> 4;
  const int srow = t >> 3, sc = (t & 7) * 8;    // 512 threads stage 64x64

  f16x8 qh[2][2];
#pragma unroll
  for (int fm = 0; fm < 2; ++fm)
#pragma unroll
    for (int kc = 0; kc < 2; ++kc) {
      const size_t qa =
          ((size_t)bh * S_LEN + qb + wq * 32 + fm * 16 + fr) * HD + kc * 32 + fg * 8;
      qh[fm][kc] = *(const f16x8*)&Qp[qa];
    }

  const size_t kbase0 = ((size_t)bh * S_LEN + srow) * HD + sc;   // + kt*64*HD
  const size_t vbase0 = ((size_t)bh * HD + srow) * S_LEN + sc;   // + kt*64

  // ------- pass 1: row sums (K dbuf: Kh / Pt-alias, 1 barrier/kt) ---------
  float rs[2] = {};
  {
    short (*Kb0)[72] = Kh;
    short (*Kb1)[72] = (short (*)[72])&Pt[0][0];   // Pt rows 0..63, dead now
    s16x8 kreg = *(const s16x8*)&Kp[kbase0];
    for (int kt = 0; kt < 16; ++kt) {
      short (*Kb)[72] = (kt & 1) ? Kb1 : Kb0;
      *(s16x8*)&Kb[srow][sc] = kreg;
      if (kt < 15)
        kreg = *(const s16x8*)&Kp[kbase0 + (size_t)(kt + 1) * 64 * HD];
      __syncthreads();
      f16x8 kh[2][2];
#pragma unroll
      for (int fn = 0; fn < 2; ++fn)
#pragma unroll
        for (int kc = 0; kc < 2; ++kc)
          kh[fn][kc] = *(const f16x8*)&Kb[wk * 32 + fn * 16 + fr][kc * 32 + fg * 8];
      f32x4 s4[2][2] = {};  // [fn][fm]: rows=k, cols=q
#pragma unroll
      for (int fn = 0; fn < 2; ++fn)
#pragma unroll
        for (int fm = 0; fm < 2; ++fm)
#pragma unroll
          for (int kc = 0; kc < 2; ++kc)
            s4[fn][fm] = mfma_f16(kh[fn][kc], qh[fm][kc], s4[fn][fm]);
#pragma unroll
      for (int fn = 0; fn < 2; ++fn)
#pragma unroll
        for (int fm = 0; fm < 2; ++fm)
#pragma unroll
          for (int r = 0; r < 4; ++r)
            rs[fm] += __expf(s4[fn][fm][r] * 0.125f);
      // no trailing barrier: next kt writes the other buffer
    }
  }
#pragma unroll
  for (int fm = 0; fm < 2; ++fm) {
    float v = rs[fm];
    v += __shfl_xor(v, 16); v += __shfl_xor(v, 32);   // sum across fg
    if (fg == 0) sums[wk][wq * 32 + fm * 16 + fr] = v;
  }
  __syncthreads();
  if (t < 128) sinv[t] = 1.0f / (sums[0][t] + sums[1][t]);
  __syncthreads();

  float pinv[2];
#pragma unroll
  for (int fm = 0; fm < 2; ++fm) pinv[fm] = sinv[wq * 32 + fm * 16 + fr];

  // ------- pass 2: scores + attn write + PV (R15-identical) ---------------
  f32x4 apv[2][2] = {};
  {
    s16x8 kreg = *(const s16x8*)&Kp[kbase0];
    s16x8 vreg = *(const s16x8*)&Vt[vbase0];
    for (int kt = 0; kt < 16; ++kt) {
      *(s16x8*)&Kh[srow][sc] = kreg;
      *(s16x8*)&Vs[srow][sc] = vreg;
      if (kt < 15) {
        kreg = *(const s16x8*)&Kp[kbase0 + (size_t)(kt + 1) * 64 * HD];
        vreg = *(const s16x8*)&Vt[vbase0 + (kt + 1) * 64];
      }
      __syncthreads();
      f16x8 kh[2][2];
#pragma unroll
      for (int fn = 0; fn < 2; ++fn)
#pragma unroll
        for (int kc = 0; kc < 2; ++kc)
          kh[fn][kc] = *(const f16x8*)&Kh[wk * 32 + fn * 16 + fr][kc * 32 + fg * 8];
      f32x4 s4[2][2] = {};  // [fn][fm]
#pragma unroll
      for (int fn = 0; fn < 2; ++fn)
#pragma unroll
        for (int fm = 0; fm < 2; ++fm)
#pragma unroll
          for (int kc = 0; kc < 2; ++kc)
            s4[fn][fm] = mfma_f16(kh[fn][kc], qh[fm][kc], s4[fn][fm]);
#pragma unroll
      for (int fm = 0; fm < 2; ++fm) {
#pragma unroll
        for (int fn = 0; fn < 2; ++fn) {
          const int kbase = wk * 32 + fn * 16 + fg * 4;
          s16x4 pk;
#pragma unroll
          for (int r = 0; r < 4; ++r)
            pk[r] = f2h(__expf(s4[fn][fm][r] * 0.125f) * pinv[fm]);
          *(s16x4*)&Pt[wq * 32 + fm * 16 + fr][kbase] = pk;
        }
      }
      __syncthreads();
      // coalesced attn store from Pt: 16 lanes = 256 B contiguous
      {
        const int r0 = t >> 4, c4 = (t & 15) * 4;
#pragma unroll
        for (int it = 0; it < 4; ++it) {
          const int q = r0 + it * 32;
          const s16x4 p4 = *(const s16x4*)&Pt[q][c4];
          float4 o;
          o.x = h2f(p4[0]); o.y = h2f(p4[1]);
          o.z = h2f(p4[2]); o.w = h2f(p4[3]);
          *(float4*)&attn[((size_t)bh * S_LEN + qb + q) * S_LEN + kt * 64 + c4] = o;
        }
      }
      f16x8 af[2][2], bv[2][2];
#pragma unroll
      for (int f = 0; f < 2; ++f)
#pragma unroll
        for (int kc = 0; kc < 2; ++kc) {
          af[f][kc] = *(const f16x8*)&Pt[wq * 32 + f * 16 + fr][kc * 32 + fg * 8];
          bv[f][kc] = *(const f16x8*)&Vs[wk * 32 + f * 16 + fr][kc * 32 + fg * 8];
        }
#pragma unroll
      for (int i = 0; i < 2; ++i)
#pragma unroll
        for (int j = 0; j < 2; ++j)
#pragma unroll
          for (int kc = 0; kc < 2; ++kc)
            apv[i][j] = mfma_f16(af[i][kc], bv[j][kc], apv[i][j]);
      __syncthreads();
    }
  }

  // ctx -> fp16 plane in K-STEP-TILED order for the O-proj DMA
#pragma unroll
  for (int i = 0; i < 2; ++i)
#pragma unroll
    for (int j = 0; j < 2; ++j) {
      const int s0 = qb + wq * 32 + i * 16 + fg * 4;
      const int d = h * HD + wk * 32 + j * 16 + fr;
#pragma unroll
      for (int r = 0; r < 4; ++r) {
        const int m = batch * S_LEN + s0 + r;
        const size_t idx =
            (((size_t)(m >> 7) * 32 + (d >> 5)) * 128 + (m & 127)) * 32 + (d & 31);
        Cp[idx] = f2h(apv[i][j][r]);
      }
    }
}

// ---------------------------------------------------------------------------
extern "C" void kernel_launch(void* const* d_in, const int* in_sizes, int n_in,
                              void* d_out, int out_size, void* d_ws, size_t ws_size,
                              hipStream_t stream) {
  const float* query = (const float*)d_in[0];
  const float* key   = (const float*)d_in[1];
  const float* value = (const float*)d_in[2];
  const float* Wq    = (const float*)d_in[3];
  const float* bq    = (const float*)d_in[4];
  const float* Wk    = (const float*)d_in[5];
  const float* bk    = (const float*)d_in[6];
  const float* Wv    = (const float*)d_in[7];
  const float* bv    = (const float*)d_in[8];
  const float* Wo    = (const float*)d_in[9];
  const float* bo    = (const float*)d_in[10];

  float* out  = (float*)d_out;                  // [8192][1024]
  float* attn = out + (size_t)MROWS * 1024;     // [128][1024][1024]

  short* apl = (short*)d_ws;                    // 3 activation planes
  short* qp  = apl + 3 * (size_t)APLANE;        // Q/K/V fp16 outputs
  short* kp  = qp + APLANE;
  short* vt  = kp + APLANE;
  short* w4  = vt + APLANE;                     // 4 packed weight planes
  short* cx  = apl + 2 * (size_t)APLANE;        // ctx aliases av-plane (dead
                                                // after qkvproj; cross-kernel)

  const dim3 blk(256);

  convall_k<<<dim3(4096, 4), blk, 0, stream>>>(query, key, value,
                                               Wq, Wk, Wv, Wo, apl, w4);
  qkvproj_k<<<dim3(512, 3), blk, 0, stream>>>(apl, w4, bq, bk, bv, qp, kp, vt);

  attn_k<<<dim3(1024), dim3(512), 0, stream>>>(qp, kp, vt, attn, cx);

  oproj_k<<<dim3(512), blk, 0, stream>>>(cx, w4 + 3 * WPLANE, bo, out);
}